// Round 1
// baseline (199.159 us; speedup 1.0000x reference)
//
#include <hip/hip_runtime.h>
#include <math.h>

// Problem constants
#define H_GRID 32
#define W_GRID 64
#define NTOK   2048      // H_GRID * W_GRID
#define NHEADS 8
#define HD     24
#define DIMC   192
#define BATCH  4

static constexpr float SCALE = 0.20412414523193154f; // 1/sqrt(24)

static __device__ __forceinline__ float4 ld4(const float* p) { return *(const float4*)p; }

// ---------------------------------------------------------------------------
// Tiled fp32 GEMM: C[M x Ncols] = A[M x 192] * W[Ncols x 192]^T + bias
// MODE 0: qkv — scatter into q/k/v workspaces laid out [B, h, N, d], q scaled.
// MODE 1: proj — direct store to out[M x 192].
// Tiles: BM=BN=64, BK=16; 256 threads; 4x4 micro-tile per thread.
// ---------------------------------------------------------------------------
template <int MODE>
__global__ __launch_bounds__(256) void gemm192(const float* __restrict__ A,
                                               const float* __restrict__ W,
                                               const float* __restrict__ bias,
                                               float* __restrict__ out,
                                               float* __restrict__ qws,
                                               float* __restrict__ kws,
                                               float* __restrict__ vws) {
    __shared__ float As[16][68];  // stride 68 floats: 16B-aligned rows, few conflicts
    __shared__ float Bs[16][68];

    const int t    = threadIdx.x;
    const int m0   = blockIdx.x * 64;
    const int j0   = blockIdx.y * 64;
    const int lrow = t >> 2;          // 0..63
    const int lk4  = (t & 3) << 2;    // 0,4,8,12
    const int ti   = (t >> 4) << 2;   // row offset in tile, 0..60
    const int tj   = (t & 15) << 2;   // col offset in tile, 0..60

    float acc[4][4] = {};

    for (int k0 = 0; k0 < 192; k0 += 16) {
        float4 av = ld4(&A[(m0 + lrow) * 192 + k0 + lk4]);
        float4 bv = ld4(&W[(j0 + lrow) * 192 + k0 + lk4]);
        __syncthreads();  // protect previous iteration's reads
        As[lk4 + 0][lrow] = av.x; As[lk4 + 1][lrow] = av.y;
        As[lk4 + 2][lrow] = av.z; As[lk4 + 3][lrow] = av.w;
        Bs[lk4 + 0][lrow] = bv.x; Bs[lk4 + 1][lrow] = bv.y;
        Bs[lk4 + 2][lrow] = bv.z; Bs[lk4 + 3][lrow] = bv.w;
        __syncthreads();
#pragma unroll
        for (int kk = 0; kk < 16; kk++) {
            float4 a = *(const float4*)&As[kk][ti];
            float4 b = *(const float4*)&Bs[kk][tj];
            float ar[4] = {a.x, a.y, a.z, a.w};
            float br[4] = {b.x, b.y, b.z, b.w};
#pragma unroll
            for (int i = 0; i < 4; i++)
#pragma unroll
                for (int j = 0; j < 4; j++) acc[i][j] += ar[i] * br[j];
        }
    }

#pragma unroll
    for (int i = 0; i < 4; i++) {
        const int m  = m0 + ti + i;
        const int b_ = m >> 11;       // batch
        const int n  = m & 2047;      // token
#pragma unroll
        for (int jj = 0; jj < 4; jj++) {
            const int col = j0 + tj + jj;
            float val = acc[i][jj] + bias[col];
            if (MODE == 0) {
                const int which = col / 192;
                const int r     = col - which * 192;
                const int head  = r / 24;
                const int d     = r - head * 24;
                const int dst   = ((b_ * 8 + head) * 2048 + n) * 24 + d;
                if (which == 0)      qws[dst] = val * SCALE;
                else if (which == 1) kws[dst] = val;
                else                 vws[dst] = val;
            } else {
                out[m * 192 + col] = val;
            }
        }
    }
}

// ---------------------------------------------------------------------------
// Local-window attention. One block (256 threads) per (b, n).
// Window: |dh|<=3, |dw|<=5 on the 32x64 grid -> <=77 keys, all heads.
// q pre-scaled by 1/sqrt(24). Output layout [B, N, 192] (head*24+d).
// ---------------------------------------------------------------------------
__global__ __launch_bounds__(256) void attn_local(const float* __restrict__ q,
                                                  const float* __restrict__ k,
                                                  const float* __restrict__ v,
                                                  float* __restrict__ aout) {
    const int bn = blockIdx.x;       // 0..8191
    const int b  = bn >> 11;
    const int n  = bn & 2047;
    const int h2 = n >> 6;
    const int w2 = n & 63;
    const int hh0 = max(h2 - 3, 0), hh1 = min(h2 + 3, H_GRID - 1);
    const int ww0 = max(w2 - 5, 0), ww1 = min(w2 + 5, W_GRID - 1);
    const int kwc = ww1 - ww0 + 1;
    const int nk  = (hh1 - hh0 + 1) * kwc;   // <= 77
    const int t   = threadIdx.x;

    __shared__ float qs[192];
    __shared__ float sc[8 * 80];
    __shared__ int   moff[77];
    __shared__ float mx[8], rs[8];

    if (t < 192) {
        const int head = t / 24, d = t - head * 24;
        qs[t] = q[((b * 8 + head) * 2048 + n) * 24 + d];
    }
    if (t < nk) {
        const int kh = hh0 + t / kwc;
        const int kw = ww0 + (t - (t / kwc) * kwc);
        moff[t] = (kh << 6) + kw;
    }
    __syncthreads();

    // Phase A: scores for (head, key)
    const int total = 8 * nk;
    for (int idx = t; idx < total; idx += 256) {
        const int head = idx / nk;
        const int kidx = idx - head * nk;
        const int m    = moff[kidx];
        const float4* kp = (const float4*)&k[(b * 8 + head) * 49152 + m * 24];
        const float4* qp = (const float4*)&qs[head * 24];
        float s = 0.f;
#pragma unroll
        for (int u = 0; u < 6; u++) {
            float4 aa = qp[u], bb = kp[u];
            s += aa.x * bb.x + aa.y * bb.y + aa.z * bb.z + aa.w * bb.w;
        }
        sc[head * 80 + kidx] = s;
    }
    __syncthreads();

    // Phase B: per-head softmax (max, exp, sum)
    if (t < 8) {
        float m_ = -1e30f;
        for (int kidx = 0; kidx < nk; kidx++) m_ = fmaxf(m_, sc[t * 80 + kidx]);
        mx[t] = m_;
    }
    __syncthreads();
    for (int idx = t; idx < 640; idx += 256) {
        sc[idx] = __expf(sc[idx] - mx[idx / 80]);  // gaps beyond nk never read
    }
    __syncthreads();
    if (t < 8) {
        float s_ = 0.f;
        for (int kidx = 0; kidx < nk; kidx++) s_ += sc[t * 80 + kidx];
        rs[t] = 1.0f / s_;
    }
    __syncthreads();

    // Phase C: output = P @ V, normalized
    if (t < 192) {
        const int head = t / 24, d = t - head * 24;
        const float* vp = &v[(b * 8 + head) * 49152 + d];
        float acc = 0.f;
        for (int kidx = 0; kidx < nk; kidx++) {
            acc += sc[head * 80 + kidx] * vp[moff[kidx] * 24];
        }
        aout[bn * 192 + t] = acc * rs[head];
    }
}

// ---------------------------------------------------------------------------
// Launch: qkv GEMM -> local attention -> proj GEMM
// Workspace: q,k,v each [4,8,2048,24] f32 (6 MB), attn out [4,2048,192] (6 MB)
// ---------------------------------------------------------------------------
extern "C" void kernel_launch(void* const* d_in, const int* in_sizes, int n_in,
                              void* d_out, int out_size, void* d_ws, size_t ws_size,
                              hipStream_t stream) {
    const float* x      = (const float*)d_in[0];
    const float* qkv_w  = (const float*)d_in[1];
    const float* qkv_b  = (const float*)d_in[2];
    const float* proj_w = (const float*)d_in[3];
    const float* proj_b = (const float*)d_in[4];
    // d_in[5] is the mask: recomputed analytically (fixed 7x11 window), unused.

    float* ws  = (float*)d_ws;
    float* qws = ws;                 // 1572864 floats
    float* kws = ws + 1572864;
    float* vws = ws + 3145728;
    float* aws = ws + 4718592;
    float* out = (float*)d_out;

    dim3 blk(256);
    dim3 g1(128, 9);  // 8192/64 x 576/64
    dim3 g3(128, 3);  // 8192/64 x 192/64

    hipLaunchKernelGGL((gemm192<0>), g1, blk, 0, stream,
                       x, qkv_w, qkv_b, (float*)nullptr, qws, kws, vws);
    hipLaunchKernelGGL(attn_local, dim3(8192), blk, 0, stream, qws, kws, vws, aws);
    hipLaunchKernelGGL((gemm192<1>), g3, blk, 0, stream,
                       aws, proj_w, proj_b, out, (float*)nullptr, (float*)nullptr, (float*)nullptr);
}

// Round 2
// 169.401 us; speedup vs baseline: 1.1757x; 1.1757x over previous
//
#include <hip/hip_runtime.h>
#include <math.h>

// Problem constants
#define H_GRID 32
#define W_GRID 64
#define NTOK   2048      // H_GRID * W_GRID
#define NHEADS 8
#define HD     24
#define DIMC   192
#define BATCH  4

static constexpr float SCALE = 0.20412414523193154f; // 1/sqrt(24)

static __device__ __forceinline__ float4 ld4(const float* p) { return *(const float4*)p; }

// ---------------------------------------------------------------------------
// Tiled fp32 GEMM: C[M x Ncols] = A[M x 192] * W[Ncols x 192]^T + bias
// MODE 0: qkv — scatter into q/k/v workspaces laid out [B, h, N, d], q scaled.
// MODE 1: proj — direct store to out[M x 192].
// Tiles: BM=BN=64, BK=16; 256 threads; 4x4 micro-tile per thread.
// ---------------------------------------------------------------------------
template <int MODE>
__global__ __launch_bounds__(256) void gemm192(const float* __restrict__ A,
                                               const float* __restrict__ W,
                                               const float* __restrict__ bias,
                                               float* __restrict__ out,
                                               float* __restrict__ qws,
                                               float* __restrict__ kws,
                                               float* __restrict__ vws) {
    __shared__ float As[16][68];
    __shared__ float Bs[16][68];

    const int t    = threadIdx.x;
    const int m0   = blockIdx.x * 64;
    const int j0   = blockIdx.y * 64;
    const int lrow = t >> 2;
    const int lk4  = (t & 3) << 2;
    const int ti   = (t >> 4) << 2;
    const int tj   = (t & 15) << 2;

    float acc[4][4] = {};

    for (int k0 = 0; k0 < 192; k0 += 16) {
        float4 av = ld4(&A[(m0 + lrow) * 192 + k0 + lk4]);
        float4 bv = ld4(&W[(j0 + lrow) * 192 + k0 + lk4]);
        __syncthreads();
        As[lk4 + 0][lrow] = av.x; As[lk4 + 1][lrow] = av.y;
        As[lk4 + 2][lrow] = av.z; As[lk4 + 3][lrow] = av.w;
        Bs[lk4 + 0][lrow] = bv.x; Bs[lk4 + 1][lrow] = bv.y;
        Bs[lk4 + 2][lrow] = bv.z; Bs[lk4 + 3][lrow] = bv.w;
        __syncthreads();
#pragma unroll
        for (int kk = 0; kk < 16; kk++) {
            float4 a = *(const float4*)&As[kk][ti];
            float4 b = *(const float4*)&Bs[kk][tj];
            float ar[4] = {a.x, a.y, a.z, a.w};
            float br[4] = {b.x, b.y, b.z, b.w};
#pragma unroll
            for (int i = 0; i < 4; i++)
#pragma unroll
                for (int j = 0; j < 4; j++) acc[i][j] += ar[i] * br[j];
        }
    }

#pragma unroll
    for (int i = 0; i < 4; i++) {
        const int m  = m0 + ti + i;
        const int b_ = m >> 11;
        const int n  = m & 2047;
#pragma unroll
        for (int jj = 0; jj < 4; jj++) {
            const int col = j0 + tj + jj;
            float val = acc[i][jj] + bias[col];
            if (MODE == 0) {
                const int which = col / 192;
                const int r     = col - which * 192;
                const int head  = r / 24;
                const int d     = r - head * 24;
                const int dst   = ((b_ * 8 + head) * 2048 + n) * 24 + d;
                if (which == 0)      qws[dst] = val * SCALE;
                else if (which == 1) kws[dst] = val;
                else                 vws[dst] = val;
            } else {
                out[m * 192 + col] = val;
            }
        }
    }
}

// ---------------------------------------------------------------------------
// Tiled local attention. One block per (batch, head, 4x8 query tile).
// Key superset window: <=10 x 18 = 180 keys staged in LDS (K transposed, V
// row-major). Scores 4q x 4k register-tiled; softmax via shfl over 8 lanes/q;
// PV with (q, d-quad) threads. q pre-scaled by 1/sqrt(24).
// Output layout [B, N, 192].
// ---------------------------------------------------------------------------
__global__ __launch_bounds__(256) void attn_tile(const float* __restrict__ q,
                                                 const float* __restrict__ k,
                                                 const float* __restrict__ v,
                                                 float* __restrict__ aout) {
    const int qtile = blockIdx.x;   // 0..63
    const int head  = blockIdx.y;   // 0..7
    const int b     = blockIdx.z;   // 0..3
    const int qh0   = (qtile >> 3) * 4;
    const int qw0   = (qtile & 7) * 8;

    const int kh0 = max(qh0 - 3, 0), kh1 = min(qh0 + 6, H_GRID - 1);
    const int kw0 = max(qw0 - 5, 0), kw1 = min(qw0 + 12, W_GRID - 1);
    const int khc = kh1 - kh0 + 1;            // <= 10
    const int kwc = kw1 - kw0 + 1;            // <= 18
    const int nk  = khc * kwc;                // <= 180

    const int t = threadIdx.x;
    const float* kbase = &k[(size_t)((b * 8 + head) * 2048) * 24];
    const float* vbase = &v[(size_t)((b * 8 + head) * 2048) * 24];
    const float* qbase = &q[(size_t)((b * 8 + head) * 2048) * 24];

    __shared__ float KsT[24][192];   // transposed K: [d][slot]
    __shared__ float Vs[180][28];    // V: [slot][d], padded
    __shared__ float qsT[24][32];    // transposed q tile: [d][ql]
    __shared__ float Sc[32][196];    // scores/probs: [ql][slot]
    __shared__ int   khw[192];       // packed (kh<<8)|kw per slot (sentinel invalid)
    __shared__ int   toks[192];      // token index per slot
    __shared__ float rs[32];         // 1/sum per query

    // ---- Phase 0: slot geometry + q tile load ----
    if (t < 192) {
        if (t < nk) {
            const int rr = t / kwc;
            const int cc = t - rr * kwc;
            const int kh = kh0 + rr, kw = kw0 + cc;
            khw[t]  = (kh << 8) | kw;
            toks[t] = (kh << 6) + kw;
        } else {
            khw[t] = 0x7F7F;   // far away -> always masked
        }
        // q tile: t = dq*32 + ql
        const int ql = t & 31, dq = t >> 5;   // dq 0..5
        const int tq = ((qh0 + (ql >> 3)) << 6) + qw0 + (ql & 7);
        float4 qv = ld4(&qbase[tq * 24 + dq * 4]);
        qsT[dq * 4 + 0][ql] = qv.x; qsT[dq * 4 + 1][ql] = qv.y;
        qsT[dq * 4 + 2][ql] = qv.z; qsT[dq * 4 + 3][ql] = qv.w;
    }
    __syncthreads();

    // ---- Phase 1: K (transposed) and V loads ----
    for (int i = t; i < 1152; i += 256) {        // 192 slots x 6 d-quads
        const int slot = i % 192;
        const int dq   = i / 192;
        if (slot < nk) {
            const int tok = toks[slot];
            float4 kv = ld4(&kbase[tok * 24 + dq * 4]);
            KsT[dq * 4 + 0][slot] = kv.x; KsT[dq * 4 + 1][slot] = kv.y;
            KsT[dq * 4 + 2][slot] = kv.z; KsT[dq * 4 + 3][slot] = kv.w;
            float4 vv = ld4(&vbase[tok * 24 + dq * 4]);
            *(float4*)&Vs[slot][dq * 4] = vv;
        }
    }
    __syncthreads();

    // ---- Phase 2: scores, 4q x 4k register tile ----
    {
        const int kq = t & 7;
        const int qg = (t >> 3) & 7;
        const int jw = t >> 6;
        for (int j = jw; j < 6; j += 4) {
            const int s0 = j * 32 + kq * 4;
            float acc[4][4] = {};
#pragma unroll
            for (int d = 0; d < 24; d++) {
                float4 q4 = *(const float4*)&qsT[d][qg * 4];
                float4 k4 = *(const float4*)&KsT[d][s0];
                float qa[4] = {q4.x, q4.y, q4.z, q4.w};
                float ka[4] = {k4.x, k4.y, k4.z, k4.w};
#pragma unroll
                for (int u = 0; u < 4; u++)
#pragma unroll
                    for (int w = 0; w < 4; w++) acc[u][w] += qa[u] * ka[w];
            }
            const int4 kh4 = *(const int4*)&khw[s0];
            const int khwv[4] = {kh4.x, kh4.y, kh4.z, kh4.w};
#pragma unroll
            for (int u = 0; u < 4; u++) {
                const int qq = qg * 4 + u;
                const int qh = qh0 + (qq >> 3);
                const int qw = qw0 + (qq & 7);
                float o[4];
#pragma unroll
                for (int w = 0; w < 4; w++) {
                    const int kh = khwv[w] >> 8, kw = khwv[w] & 255;
                    const bool valid = (abs(kh - qh) <= 3) && (abs(kw - qw) <= 5);
                    o[w] = valid ? acc[u][w] : -1e30f;
                }
                *(float4*)&Sc[qq][s0] = make_float4(o[0], o[1], o[2], o[3]);
            }
        }
    }
    __syncthreads();

    // ---- Phase 3: softmax per query (8 lanes per q) ----
    {
        const int ql = t >> 3, kg = t & 7;
        float vals[24];
        float m = -1e30f;
#pragma unroll
        for (int i = 0; i < 24; i++) {
            vals[i] = Sc[ql][kg + 8 * i];
            m = fmaxf(m, vals[i]);
        }
        m = fmaxf(m, __shfl_xor(m, 1));
        m = fmaxf(m, __shfl_xor(m, 2));
        m = fmaxf(m, __shfl_xor(m, 4));
        float s = 0.f;
#pragma unroll
        for (int i = 0; i < 24; i++) {
            float p = __expf(vals[i] - m);
            s += p;
            Sc[ql][kg + 8 * i] = p;
        }
        s += __shfl_xor(s, 1);
        s += __shfl_xor(s, 2);
        s += __shfl_xor(s, 4);
        if (kg == 0) rs[ql] = 1.0f / s;
    }
    __syncthreads();

    // ---- Phase 4: PV, (q, d-quad) threads over valid window ----
    if (t < 192) {
        const int ql = t / 6, dq = t - (t / 6) * 6;
        const int qh = qh0 + (ql >> 3);
        const int qw = qw0 + (ql & 7);
        const int r0 = max(qh - 3, 0) - kh0, r1 = min(qh + 3, H_GRID - 1) - kh0;
        const int c0 = max(qw - 5, 0) - kw0, c1 = min(qw + 5, W_GRID - 1) - kw0;
        float4 o = make_float4(0.f, 0.f, 0.f, 0.f);
        for (int rr = r0; rr <= r1; rr++) {
            const int sbase = rr * kwc;
            for (int cc = c0; cc <= c1; cc++) {
                const float p = Sc[ql][sbase + cc];
                const float4 vv = *(const float4*)&Vs[sbase + cc][dq * 4];
                o.x += p * vv.x; o.y += p * vv.y; o.z += p * vv.z; o.w += p * vv.w;
            }
        }
        const float r = rs[ql];
        const int tq = ((qh0 + (ql >> 3)) << 6) + qw0 + (ql & 7);
        float4 res = make_float4(o.x * r, o.y * r, o.z * r, o.w * r);
        *(float4*)&aout[(size_t)(b * 2048 + tq) * 192 + head * 24 + dq * 4] = res;
    }
}

// ---------------------------------------------------------------------------
// Launch: qkv GEMM -> tiled local attention -> proj GEMM
// ---------------------------------------------------------------------------
extern "C" void kernel_launch(void* const* d_in, const int* in_sizes, int n_in,
                              void* d_out, int out_size, void* d_ws, size_t ws_size,
                              hipStream_t stream) {
    const float* x      = (const float*)d_in[0];
    const float* qkv_w  = (const float*)d_in[1];
    const float* qkv_b  = (const float*)d_in[2];
    const float* proj_w = (const float*)d_in[3];
    const float* proj_b = (const float*)d_in[4];
    // d_in[5] mask: recomputed analytically (fixed 7x11 window), unused.

    float* ws  = (float*)d_ws;
    float* qws = ws;                 // [4,8,2048,24]
    float* kws = ws + 1572864;
    float* vws = ws + 3145728;
    float* aws = ws + 4718592;       // [4,2048,192]
    float* out = (float*)d_out;

    dim3 blk(256);
    dim3 g1(128, 9);  // 8192/64 x 576/64
    dim3 g3(128, 3);  // 8192/64 x 192/64

    hipLaunchKernelGGL((gemm192<0>), g1, blk, 0, stream,
                       x, qkv_w, qkv_b, (float*)nullptr, qws, kws, vws);
    hipLaunchKernelGGL(attn_tile, dim3(64, 8, 4), blk, 0, stream, qws, kws, vws, aws);
    hipLaunchKernelGGL((gemm192<1>), g3, blk, 0, stream,
                       aws, proj_w, proj_b, out, (float*)nullptr, (float*)nullptr, (float*)nullptr);
}